// Round 8
// baseline (573.326 us; speedup 1.0000x reference)
//
#include <hip/hip_runtime.h>
#include <hip/hip_bf16.h>
#include <math.h>

#define BB 64
#define CC 256
#define TT 32
#define HH 7
#define WW 7
#define HW 49
#define NN 1568          // T*H*W
#define KV 97
#define KN 300
#define DD 512
#define NTOK 392
#define TOTAL (BB*TT*HW) // 100352
#define BCAP 256         // boundary-bin compaction capacity per head

typedef float f32x4 __attribute__((ext_vector_type(4)));
typedef short bf16x8 __attribute__((ext_vector_type(8)));

#define GLDS(g, l) __builtin_amdgcn_global_load_lds(                          \
    (const __attribute__((address_space(1))) void*)(g),                       \
    (__attribute__((address_space(3))) void*)(l), 16, 0, 0)

// ---------------- K1: pure transpose x -> xp (bf16, 81-padded) + wb ---------
// R2-proven (total-best config, 411.6 us). Block = (b, 32-channel chunk,
// 8-frame chunk). Per channel the block reads 392 CONTIGUOUS floats; writes
// 64 B (32 bf16 channels) per output position.
__global__ __launch_bounds__(256) void k_tr(
        const float* __restrict__ x, __hip_bfloat16* __restrict__ xp,
        const float* __restrict__ cw, __hip_bfloat16* __restrict__ wb,
        int* __restrict__ counter) {
    __shared__ float xs[392 * 33];      // 51,744 B; [tq][ch], odd pitch
    int bid = blockIdx.x;               // 0..2047
    int tid = threadIdx.x;              // 0..255
    if (bid == 0 && tid == 0) *counter = 0;   // k_bce completion counter

    // wb slice: elements [bid*576, bid*576+576)  (stride-9 gather, tiny)
    {
        int base = bid * 576;
        #pragma unroll
        for (int r = 0; r < 3; ++r) {
            int o = base + r * 256 + tid;
            if (o < base + 576) {
                int kk = o / (DD * CC);
                int rem = o - kk * (DD * CC);
                int d = rem >> 8, c = rem & 255;
                wb[o] = __float2bfloat16(cw[(d * CC + c) * 9 + kk]);
            }
        }
    }

    int b  = bid >> 5;          // 0..63
    int cc = (bid >> 2) & 7;    // 0..7   channel chunk
    int tc = bid & 3;           // 0..3   frame chunk
    int c0 = cc << 5;           // channel base (32 per block)
    int t0 = tc << 3;           // frame base   (8 per block)

    // phase 1: fully-contiguous float4 loads. 3136 float4 = 32 ch x 98.
    const float* xbase = x + ((size_t)((b * CC + c0) * TT + t0)) * HW;
    const float4* xb4 = (const float4*)xbase;
    for (int base = 0; base < 3072; base += 1024) {
        float4 v[4]; int li[4];
        #pragma unroll
        for (int j = 0; j < 4; ++j) {
            int idx = base + j * 256 + tid;
            v[j] = xb4[idx];
            int ch = idx / 98, o4 = idx - ch * 98;
            li[j] = (o4 * 4) * 33 + ch;
        }
        #pragma unroll
        for (int j = 0; j < 4; ++j) {
            xs[li[j]     ] = v[j].x;
            xs[li[j] + 33] = v[j].y;
            xs[li[j] + 66] = v[j].z;
            xs[li[j] + 99] = v[j].w;
        }
    }
    {
        int idx = 3072 + tid;
        if (idx < 3136) {
            float4 v = xb4[idx];
            int ch = idx / 98, o4 = idx - ch * 98;
            int li = (o4 * 4) * 33 + ch;
            xs[li] = v.x; xs[li + 33] = v.y; xs[li + 66] = v.z; xs[li + 99] = v.w;
        }
    }
    __syncthreads();

    // phase 2: store xp slices. 8 frames x 81 positions x 4 chan-quarters.
    __hip_bfloat16* xpb = xp + ((size_t)(b * TT + t0) * 81) * 256 + c0;
    for (int u = tid; u < 2592; u += 256) {
        int pos = u >> 2, cq = u & 3;
        int tt = pos / 81, p = pos - tt * 81;
        int hh = p / 9, ww = p - (p / 9) * 9;
        bool inb = (hh >= 1 && hh <= 7 && ww >= 1 && ww <= 7);
        const float* row = xs + (tt * 49 + (hh - 1) * 7 + (ww - 1)) * 33 + cq * 8;
        bf16x8 pack;
        #pragma unroll
        for (int j = 0; j < 8; ++j) {
            float v = inb ? row[j] : 0.f;
            __hip_bfloat16 bv = __float2bfloat16(v);
            pack[j] = *reinterpret_cast<short*>(&bv);
        }
        *reinterpret_cast<bf16x8*>(xpb + (size_t)(tt * 81 + p) * 256 + cq * 8) = pack;
    }
}

// ---------------- cam selection (runs as blocks 0..63 of k_gemm_a) ----------
__device__ __forceinline__ int binof(float v) {
    int i = (int)(v * 1024.f);
    return i < 0 ? 0 : (i > 1023 ? 1023 : i);
}

// cam_block computes its own argmax + CAM rows directly from x (per-channel
// fully-contiguous float4 streams, hidden under the concurrent GEMM blocks),
// then runs the selection pipeline.
__device__ void cam_block(int b, int tid, char* smem,
                          const float* __restrict__ x,
                          const float* __restrict__ pv, const float* __restrict__ pn,
                          const float* __restrict__ wpv, const float* __restrict__ wpn,
                          float* __restrict__ cam) {
    float* rv = (float*)smem;                 // 6272 B
    float* rn = (float*)(smem + 6272);        // 6272 B
    int* h = (int*)(smem + 12544);            // 4096 B, packed lo16 v / hi16 n
    int* tsum = (int*)(smem + 16640);         // 1024 B
    float* lval_v = (float*)(smem + 17664);   // 1024 B
    int* lidx_v = (int*)(smem + 18688);       // 1024 B
    float* lval_n = (float*)(smem + 19712);   // 1024 B
    int* lidx_n = (int*)(smem + 20736);       // 1024 B
    float* wred = (float*)(smem + 21760);     // 64 B  [wave][4]
    int* sc = (int*)(smem + 21824);           // 6 ints
    float* wvs = (float*)(smem + 21888);      // 1024 B
    float* wns = (float*)(smem + 22912);      // 1024 B
    int* cls2 = (int*)(smem + 23936);         // 8 B

    int lane = tid & 63;
    if (tid < 128) {
        int head = tid >> 6;
        const float* r = head ? (pn + b * KN) : (pv + b * KV);
        int K = head ? KN : KV;
        float best = -1e30f; int bi = 0x7fffffff;
        for (int k = lane; k < K; k += 64) {
            float v = r[k];
            if (v > best || (v == best && k < bi)) { best = v; bi = k; }
        }
        #pragma unroll
        for (int off = 32; off >= 1; off >>= 1) {
            float ov = __shfl_xor(best, off);
            int oi = __shfl_xor(bi, off);
            if (ov > best || (ov == best && oi < bi)) { best = ov; bi = oi; }
        }
        if (lane == 0) cls2[head] = bi;
    }
    __syncthreads();
    wvs[tid] = wpv[cls2[0] * CC + tid];
    wns[tid] = wpn[cls2[1] * CC + tid];
    __syncthreads();

    {
        const f32x4* xb4 = (const f32x4*)(x + (size_t)b * CC * NN);
        bool two = tid < (392 - 256);
        f32x4 av0 = {0.f,0.f,0.f,0.f}, an0 = {0.f,0.f,0.f,0.f};
        f32x4 av1 = {0.f,0.f,0.f,0.f}, an1 = {0.f,0.f,0.f,0.f};
        for (int c = 0; c < CC; ++c) {
            float wv = wvs[c], wn = wns[c];
            const f32x4* rowc = xb4 + (size_t)c * 392;
            f32x4 u0 = rowc[tid];
            #pragma unroll
            for (int r = 0; r < 4; ++r) {
                av0[r] = fmaf(wv, u0[r], av0[r]);
                an0[r] = fmaf(wn, u0[r], an0[r]);
            }
            if (two) {
                f32x4 u1 = rowc[tid + 256];
                #pragma unroll
                for (int r = 0; r < 4; ++r) {
                    av1[r] = fmaf(wv, u1[r], av1[r]);
                    an1[r] = fmaf(wn, u1[r], an1[r]);
                }
            }
        }
        *reinterpret_cast<f32x4*>(rv + 4 * tid) = av0;
        *reinterpret_cast<f32x4*>(rn + 4 * tid) = an0;
        if (two) {
            *reinterpret_cast<f32x4*>(rv + 4 * (tid + 256)) = av1;
            *reinterpret_cast<f32x4*>(rn + 4 * (tid + 256)) = an1;
        }
    }
    __syncthreads();

    float mnv = 1e30f, mxv = -1e30f, mnn = 1e30f, mxn = -1e30f;
    for (int n = tid; n < NN; n += 256) {
        float v = rv[n]; mnv = fminf(mnv, v); mxv = fmaxf(mxv, v);
        float u = rn[n]; mnn = fminf(mnn, u); mxn = fmaxf(mxn, u);
    }
    #pragma unroll
    for (int off = 32; off >= 1; off >>= 1) {
        mnv = fminf(mnv, __shfl_xor(mnv, off));
        mxv = fmaxf(mxv, __shfl_xor(mxv, off));
        mnn = fminf(mnn, __shfl_xor(mnn, off));
        mxn = fmaxf(mxn, __shfl_xor(mxn, off));
    }
    if ((tid & 63) == 0) {
        int wid = tid >> 6;
        wred[wid * 4 + 0] = mnv; wred[wid * 4 + 1] = mxv;
        wred[wid * 4 + 2] = mnn; wred[wid * 4 + 3] = mxn;
    }
    if (tid == 0) { sc[0] = 0; sc[1] = 0; }
    __syncthreads();
    mnv = fminf(fminf(wred[0], wred[4]), fminf(wred[8], wred[12]));
    mxv = fmaxf(fmaxf(wred[1], wred[5]), fmaxf(wred[9], wred[13]));
    mnn = fminf(fminf(wred[2], wred[6]), fminf(wred[10], wred[14]));
    mxn = fmaxf(fmaxf(wred[3], wred[7]), fmaxf(wred[11], wred[15]));
    float iv = 1.f / (mxv - mnv), inn = 1.f / (mxn - mnn);

    for (int n = tid; n < NN; n += 256) {
        rv[n] = (rv[n] - mnv) * iv;
        rn[n] = (rn[n] - mnn) * inn;
    }
    for (int i = tid; i < 1024; i += 256) h[i] = 0;
    __syncthreads();
    for (int n = tid; n < NN; n += 256) {
        atomicAdd(&h[binof(rv[n])], 1);
        atomicAdd(&h[binof(rn[n])], 1 << 16);
    }
    __syncthreads();

    int h0 = h[4 * tid], h1 = h[4 * tid + 1], h2 = h[4 * tid + 2], h3 = h[4 * tid + 3];
    tsum[tid] = h0 + h1 + h2 + h3;
    __syncthreads();
    for (int off = 1; off < 256; off <<= 1) {
        int add = (tid + off < 256) ? tsum[tid + off] : 0;
        __syncthreads();
        tsum[tid] += add;
        __syncthreads();
    }
    {
        int scur = tsum[tid];
        int hk[4] = {h0, h1, h2, h3};
        #pragma unroll
        for (int k = 0; k < 4; ++k) {
            int snext = scur - hk[k];
            int scv = scur & 0xffff, ncv = snext & 0xffff;
            int sh = scur >> 16, nh = snext >> 16;
            if (scv >= NTOK && ncv < NTOK) { sc[2] = 4 * tid + k; sc[3] = ncv; }
            if (sh >= NTOK && nh < NTOK) { sc[4] = 4 * tid + k; sc[5] = nh; }
            scur = snext;
        }
    }
    __syncthreads();
    int bsv = sc[2], abv = sc[3], bsn = sc[4], abn = sc[5];

    for (int n = tid; n < NN; n += 256) {
        float v = rv[n]; int bv = binof(v);
        if (bv < bsv) rv[n] = 0.f;
        else if (bv == bsv) {
            int s = atomicAdd(&sc[0], 1);
            if (s < BCAP) { lval_v[s] = v; lidx_v[s] = n; }
        }
        float u = rn[n]; int bu = binof(u);
        if (bu < bsn) rn[n] = 0.f;
        else if (bu == bsn) {
            int s = atomicAdd(&sc[1], 1);
            if (s < BCAP) { lval_n[s] = u; lidx_n[s] = n; }
        }
    }
    __syncthreads();
    int Lv = sc[0] < BCAP ? sc[0] : BCAP;
    int Ln = sc[1] < BCAP ? sc[1] : BCAP;
    for (int i = tid; i < Lv; i += 256) {
        float vi = lval_v[i]; int ni = lidx_v[i]; int r = 0;
        for (int j = 0; j < Lv; ++j) {
            float vj = lval_v[j]; int nj = lidx_v[j];
            r += (vj > vi || (vj == vi && nj < ni)) ? 1 : 0;
        }
        rv[ni] = (r < NTOK - abv) ? vi : 0.f;
    }
    for (int i = tid; i < Ln; i += 256) {
        float vi = lval_n[i]; int ni = lidx_n[i]; int r = 0;
        for (int j = 0; j < Ln; ++j) {
            float vj = lval_n[j]; int nj = lidx_n[j];
            r += (vj > vi || (vj == vi && nj < ni)) ? 1 : 0;
        }
        rn[ni] = (r < NTOK - abn) ? vi : 0.f;
    }
    __syncthreads();
    for (int n = tid; n < NN; n += 256) cam[b * NN + n] = fmaxf(rv[n], rn[n]);
}

// ---------------- GEMM tile body (R2-proven core, unchanged math) -----------
__device__ void gemm_tile(int gid, int tid, char* smem,
                          const __hip_bfloat16* __restrict__ xp,
                          const __hip_bfloat16* __restrict__ wb,
                          const float* __restrict__ convb,
                          const float* __restrict__ scorew,
                          float* __restrict__ pl) {
    char* As = smem;             // [row 0..127][seg 0..7] bf16x8, swizzled
    char* Bs = smem + 16384;     // [d'  0..127][seg 0..7]
    int xcd = gid & 7;
    int local = gid >> 3;        // 0..391
    int mtile = xcd * 98 + (local >> 2);
    int nblk = local & 3;
    int m0 = mtile * 128;
    int n0 = nblk * 128;
    int lane = tid & 63, wv = tid >> 6;
    int wm = wv >> 1, wn = wv & 1;
    int ln = lane & 15, qd = lane >> 4;

    int rrow = tid >> 3;
    int segst = ((tid & 7) ^ (rrow & 7)) * 8;     // element offset in row
    int bt_[4], hh_[4], ww_[4];
    const __hip_bfloat16* bptr[4];
    #pragma unroll
    for (int j = 0; j < 4; ++j) {
        int m = m0 + j * 32 + rrow;
        int bt = m / HW, q = m - bt * HW;
        bt_[j] = bt; hh_[j] = q / WW; ww_[j] = q - (q / WW) * WW;
        bptr[j] = wb + (size_t)(n0 + j * 32 + rrow) * 256 + segst;
    }

    int swz = ln & 7;
    int offk[2] = {((0 + qd) ^ swz) * 16, ((4 + qd) ^ swz) * 16};

    f32x4 acc[4][4];
    #pragma unroll
    for (int i = 0; i < 4; ++i)
        #pragma unroll
        for (int j = 0; j < 4; ++j) acc[i][j] = (f32x4){0.f, 0.f, 0.f, 0.f};

    for (int kk = 0; kk < 9; ++kk) {
        int kh = kk / 3, kw = kk - (kk / 3) * 3;
        const __hip_bfloat16* aptr[4];
        #pragma unroll
        for (int j = 0; j < 4; ++j)
            aptr[j] = xp + ((size_t)bt_[j] * 81 + (hh_[j] + kh) * 9 + (ww_[j] + kw)) * 256 + segst;
        const size_t boff = (size_t)kk * (DD * 256);
        #pragma unroll
        for (int c0 = 0; c0 < 256; c0 += 64) {
            __syncthreads();
            #pragma unroll
            for (int j = 0; j < 4; ++j) {
                GLDS(aptr[j] + c0, As + j * 4096 + tid * 16);
                GLDS(bptr[j] + boff + c0, Bs + j * 4096 + tid * 16);
            }
            __syncthreads();
            #pragma unroll
            for (int k2 = 0; k2 < 2; ++k2) {
                bf16x8 af[4], bfr[4];
                #pragma unroll
                for (int i = 0; i < 4; ++i)
                    af[i] = *(const bf16x8*)(As + (wm * 64 + i * 16 + ln) * 128 + offk[k2]);
                #pragma unroll
                for (int j = 0; j < 4; ++j)
                    bfr[j] = *(const bf16x8*)(Bs + (wn * 64 + j * 16 + ln) * 128 + offk[k2]);
                #pragma unroll
                for (int i = 0; i < 4; ++i)
                    #pragma unroll
                    for (int j = 0; j < 4; ++j)
                        acc[i][j] = __builtin_amdgcn_mfma_f32_16x16x32_bf16(af[i], bfr[j], acc[i][j], 0, 0, 0);
            }
        }
    }

    float swr[4], cbr[4];
    #pragma unroll
    for (int j = 0; j < 4; ++j) {
        int n = n0 + wn * 64 + j * 16 + ln;
        swr[j] = scorew[n];
        cbr[j] = convb[n];
    }
    float* dst = pl + (size_t)(nblk * 2 + wn) * TOTAL;
    #pragma unroll
    for (int i = 0; i < 4; ++i) {
        #pragma unroll
        for (int r = 0; r < 4; ++r) {
            float v = 0.f;
            #pragma unroll
            for (int j = 0; j < 4; ++j) {
                float h1 = acc[i][j][r] + cbr[j];
                h1 = h1 > 0.f ? h1 : 0.f;
                v = fmaf(swr[j], h1, v);
            }
            v += __shfl_xor(v, 1);
            v += __shfl_xor(v, 2);
            v += __shfl_xor(v, 4);
            v += __shfl_xor(v, 8);
            if (ln == 0)
                dst[m0 + wm * 64 + i * 16 + qd * 4 + r] = v;
        }
    }
}

// ---------------- K5a/K5b: GEMM split into two dispatches (R8 diagnostic) ---
// Halving each dispatch to ~118 us drops the top-5 reveal threshold below the
// invariant ~160-190 us remainder: if k_tr is really that long it MUST now
// appear in the counter table (H1); if it stays absent, k_tr < 118 us and the
// remainder is dominated by overhead (H2). gid offset 1536 is %8==0 so the
// XCD map is bit-identical to the single-dispatch version.
__global__ __launch_bounds__(256, 3) void k_gemm_a(
        const __hip_bfloat16* __restrict__ xp, const __hip_bfloat16* __restrict__ wb,
        const float* __restrict__ convb, const float* __restrict__ scorew,
        float* __restrict__ pl,
        const float* __restrict__ x,
        const float* __restrict__ pv, const float* __restrict__ pn,
        const float* __restrict__ wpv, const float* __restrict__ wpn,
        float* __restrict__ cam) {
    __shared__ char smem[32768];
    int tid = threadIdx.x;
    int bid = blockIdx.x;        // 0..1599
    if (bid < 64) { cam_block(bid, tid, smem, x, pv, pn, wpv, wpn, cam); return; }
    gemm_tile(bid - 64, tid, smem, xp, wb, convb, scorew, pl);   // gid 0..1535
}

__global__ __launch_bounds__(256, 3) void k_gemm_b(
        const __hip_bfloat16* __restrict__ xp, const __hip_bfloat16* __restrict__ wb,
        const float* __restrict__ convb, const float* __restrict__ scorew,
        float* __restrict__ pl) {
    __shared__ char smem[32768];
    gemm_tile(blockIdx.x + 1536, threadIdx.x, smem, xp, wb, convb, scorew, pl);
}

// ---------------- K6: slot-sum + BCE + grid reduction (last block) ----------
__global__ __launch_bounds__(256) void k_bce(
        const float* __restrict__ pl, const float* __restrict__ cam,
        const float* __restrict__ sb, float* __restrict__ part,
        int* __restrict__ counter, float* __restrict__ out) {
    __shared__ float sbuf[256];
    __shared__ int isLast;
    int tid = threadIdx.x;
    int m = blockIdx.x * 256 + tid;
    float l = sb[0];
    #pragma unroll
    for (int s = 0; s < 8; ++s) l += pl[(size_t)s * TOTAL + m];
    float y = cam[m];
    float v = fmaxf(l, 0.f) - l * y + log1pf(expf(-fabsf(l)));
    sbuf[tid] = v; __syncthreads();
    for (int k = 128; k > 0; k >>= 1) {
        if (tid < k) sbuf[tid] += sbuf[tid + k];
        __syncthreads();
    }
    if (tid == 0) {
        part[blockIdx.x] = sbuf[0];
        __threadfence();
        int d = atomicAdd(counter, 1);
        isLast = (d == 391);
    }
    __syncthreads();
    if (isLast) {
        float s = 0.f;
        for (int i = tid; i < 392; i += 256) s += part[i];
        sbuf[tid] = s; __syncthreads();
        for (int k = 128; k > 0; k >>= 1) {
            if (tid < k) sbuf[tid] += sbuf[tid + k];
            __syncthreads();
        }
        if (tid == 0) out[0] = sbuf[0] * (1.0f / (float)TOTAL);
    }
}

extern "C" void kernel_launch(void* const* d_in, const int* in_sizes, int n_in,
                              void* d_out, int out_size, void* d_ws, size_t ws_size,
                              hipStream_t stream) {
    const float* x   = (const float*)d_in[0];
    const float* pv  = (const float*)d_in[1];
    const float* pn  = (const float*)d_in[2];
    const float* wpv = (const float*)d_in[3];
    const float* wpn = (const float*)d_in[4];
    const float* cw  = (const float*)d_in[5];
    const float* cb  = (const float*)d_in[6];
    const float* sw  = (const float*)d_in[7];
    const float* sb  = (const float*)d_in[8];

    char* w8 = (char*)d_ws;
    __hip_bfloat16* xp  = (__hip_bfloat16*)w8;                  // 84,934,656 B
    __hip_bfloat16* wb  = (__hip_bfloat16*)(w8 + 84934656);     //  2,359,296 B
    float* pl      = (float*)(w8 + 87293952);                   //  3,211,264 B
    float* cam     = (float*)(w8 + 90505216);                   //    401,408 B
    float* part    = (float*)(w8 + 90906624);                   //      1,568 B
    int*   counter = (int*)(w8 + 90908192);                     //          4 B

    k_tr<<<2048, 256, 0, stream>>>(x, xp, cw, wb, counter);
    k_gemm_a<<<64 + 1536, 256, 0, stream>>>(xp, wb, cb, sw, pl,
                                            x, pv, pn, wpv, wpn, cam);
    k_gemm_b<<<1600, 256, 0, stream>>>(xp, wb, cb, sw, pl);
    k_bce<<<392, 256, 0, stream>>>(pl, cam, sb, part, counter, (float*)d_out);
}

// Round 9
// 391.578 us; speedup vs baseline: 1.4641x; 1.4641x over previous
//
#include <hip/hip_runtime.h>
#include <hip/hip_bf16.h>
#include <math.h>

#define BB 64
#define CC 256
#define TT 32
#define HH 7
#define WW 7
#define HW 49
#define NN 1568          // T*H*W
#define KV 97
#define KN 300
#define DD 512
#define NTOK 392
#define TOTAL (BB*TT*HW) // 100352
#define BCAP 256         // boundary-bin compaction capacity per head

typedef float f32x4 __attribute__((ext_vector_type(4)));
typedef short bf16x8 __attribute__((ext_vector_type(8)));

#define GLDS(g, l) __builtin_amdgcn_global_load_lds(                          \
    (const __attribute__((address_space(1))) void*)(g),                       \
    (__attribute__((address_space(3))) void*)(l), 16, 0, 0)

// ---------------- K1: transpose x -> xp (bf16, HALO-FREE 49-pos) + wb -------
// R2-proven access pattern; R9 drops the 81-position zero padding: xp is now
// [bt][49][256] bf16 (51.4 MB, was 85). k_tr writes 40% less; the GEMM
// redirects halo lanes to a zero buffer instead (per-lane GLDS source).
__global__ __launch_bounds__(256) void k_tr(
        const float* __restrict__ x, __hip_bfloat16* __restrict__ xp,
        const float* __restrict__ cw, __hip_bfloat16* __restrict__ wb,
        int* __restrict__ counter, float* __restrict__ zbuf) {
    __shared__ float xs[392 * 33];      // 51,744 B; [tq][ch], odd pitch
    int bid = blockIdx.x;               // 0..2047
    int tid = threadIdx.x;              // 0..255
    if (bid == 0) {
        if (tid == 0) *counter = 0;     // k_bce completion counter
        if (tid < 64) reinterpret_cast<float4*>(zbuf)[tid] = (float4){0.f, 0.f, 0.f, 0.f};
    }

    // wb slice: elements [bid*576, bid*576+576)  (stride-9 gather, tiny)
    {
        int base = bid * 576;
        #pragma unroll
        for (int r = 0; r < 3; ++r) {
            int o = base + r * 256 + tid;
            if (o < base + 576) {
                int kk = o / (DD * CC);
                int rem = o - kk * (DD * CC);
                int d = rem >> 8, c = rem & 255;
                wb[o] = __float2bfloat16(cw[(d * CC + c) * 9 + kk]);
            }
        }
    }

    int b  = bid >> 5;          // 0..63
    int cc = (bid >> 2) & 7;    // 0..7   channel chunk
    int tc = bid & 3;           // 0..3   frame chunk
    int c0 = cc << 5;           // channel base (32 per block)
    int t0 = tc << 3;           // frame base   (8 per block)

    // phase 1: fully-contiguous float4 loads. 3136 float4 = 32 ch x 98.
    const float* xbase = x + ((size_t)((b * CC + c0) * TT + t0)) * HW;
    const float4* xb4 = (const float4*)xbase;
    for (int base = 0; base < 3072; base += 1024) {
        float4 v[4]; int li[4];
        #pragma unroll
        for (int j = 0; j < 4; ++j) {
            int idx = base + j * 256 + tid;
            v[j] = xb4[idx];
            int ch = idx / 98, o4 = idx - ch * 98;
            li[j] = (o4 * 4) * 33 + ch;
        }
        #pragma unroll
        for (int j = 0; j < 4; ++j) {
            xs[li[j]     ] = v[j].x;
            xs[li[j] + 33] = v[j].y;
            xs[li[j] + 66] = v[j].z;
            xs[li[j] + 99] = v[j].w;
        }
    }
    {
        int idx = 3072 + tid;
        if (idx < 3136) {
            float4 v = xb4[idx];
            int ch = idx / 98, o4 = idx - ch * 98;
            int li = (o4 * 4) * 33 + ch;
            xs[li] = v.x; xs[li + 33] = v.y; xs[li + 66] = v.z; xs[li + 99] = v.w;
        }
    }
    __syncthreads();

    // phase 2: store xp slices. 8 frames x 49 positions x 4 chan-quarters
    // (no halo math, 40% fewer chunks than the 81-pos layout).
    __hip_bfloat16* xpb = xp + ((size_t)(b * TT + t0) * HW) * 256 + c0;
    for (int u = tid; u < 1568; u += 256) {
        int pos = u >> 2, cq = u & 3;           // pos 0..391 = tq directly
        const float* row = xs + pos * 33 + cq * 8;
        bf16x8 pack;
        #pragma unroll
        for (int j = 0; j < 8; ++j) {
            __hip_bfloat16 bv = __float2bfloat16(row[j]);
            pack[j] = *reinterpret_cast<short*>(&bv);
        }
        *reinterpret_cast<bf16x8*>(xpb + (size_t)pos * 256 + cq * 8) = pack;
    }
}

// ---------------- cam selection (runs as blocks 0..63 of k_gemm) ------------
__device__ __forceinline__ int binof(float v) {
    int i = (int)(v * 1024.f);
    return i < 0 ? 0 : (i > 1023 ? 1023 : i);
}

// R9: the row-compute c-loop is 4-deep load-batched (8 global loads in
// flight/thread) -- R8's split proved cam_block is a ~228 us serial chain
// co-critical with the GEMM; the rolled loop was latency-bound on its
// 1.6 MB x-read. Per-accumulator FMA order unchanged (bit-exact).
__device__ void cam_block(int b, int tid, char* smem,
                          const float* __restrict__ x,
                          const float* __restrict__ pv, const float* __restrict__ pn,
                          const float* __restrict__ wpv, const float* __restrict__ wpn,
                          float* __restrict__ cam) {
    float* rv = (float*)smem;                 // 6272 B
    float* rn = (float*)(smem + 6272);        // 6272 B
    int* h = (int*)(smem + 12544);            // 4096 B, packed lo16 v / hi16 n
    int* tsum = (int*)(smem + 16640);         // 1024 B
    float* lval_v = (float*)(smem + 17664);   // 1024 B
    int* lidx_v = (int*)(smem + 18688);       // 1024 B
    float* lval_n = (float*)(smem + 19712);   // 1024 B
    int* lidx_n = (int*)(smem + 20736);       // 1024 B
    float* wred = (float*)(smem + 21760);     // 64 B  [wave][4]
    int* sc = (int*)(smem + 21824);           // 6 ints
    float* wvs = (float*)(smem + 21888);      // 1024 B
    float* wns = (float*)(smem + 22912);      // 1024 B
    int* cls2 = (int*)(smem + 23936);         // 8 B

    int lane = tid & 63;
    if (tid < 128) {
        int head = tid >> 6;
        const float* r = head ? (pn + b * KN) : (pv + b * KV);
        int K = head ? KN : KV;
        float best = -1e30f; int bi = 0x7fffffff;
        for (int k = lane; k < K; k += 64) {
            float v = r[k];
            if (v > best || (v == best && k < bi)) { best = v; bi = k; }
        }
        #pragma unroll
        for (int off = 32; off >= 1; off >>= 1) {
            float ov = __shfl_xor(best, off);
            int oi = __shfl_xor(bi, off);
            if (ov > best || (ov == best && oi < bi)) { best = ov; bi = oi; }
        }
        if (lane == 0) cls2[head] = bi;
    }
    __syncthreads();
    wvs[tid] = wpv[cls2[0] * CC + tid];
    wns[tid] = wpn[cls2[1] * CC + tid];
    __syncthreads();

    {
        const f32x4* p0 = (const f32x4*)(x + (size_t)b * CC * NN) + tid;
        bool two = tid < (392 - 256);
        f32x4 av0 = {0.f,0.f,0.f,0.f}, an0 = {0.f,0.f,0.f,0.f};
        f32x4 av1 = {0.f,0.f,0.f,0.f}, an1 = {0.f,0.f,0.f,0.f};
        for (int c = 0; c < CC; c += 4) {
            f32x4 u0[4], u1[4];
            #pragma unroll
            for (int d = 0; d < 4; ++d) u0[d] = p0[(size_t)(c + d) * 392];
            if (two) {
                #pragma unroll
                for (int d = 0; d < 4; ++d) u1[d] = p0[(size_t)(c + d) * 392 + 256];
            }
            #pragma unroll
            for (int d = 0; d < 4; ++d) {
                float wv = wvs[c + d], wn = wns[c + d];
                #pragma unroll
                for (int r = 0; r < 4; ++r) {
                    av0[r] = fmaf(wv, u0[d][r], av0[r]);
                    an0[r] = fmaf(wn, u0[d][r], an0[r]);
                }
                if (two) {
                    #pragma unroll
                    for (int r = 0; r < 4; ++r) {
                        av1[r] = fmaf(wv, u1[d][r], av1[r]);
                        an1[r] = fmaf(wn, u1[d][r], an1[r]);
                    }
                }
            }
        }
        *reinterpret_cast<f32x4*>(rv + 4 * tid) = av0;
        *reinterpret_cast<f32x4*>(rn + 4 * tid) = an0;
        if (two) {
            *reinterpret_cast<f32x4*>(rv + 4 * (tid + 256)) = av1;
            *reinterpret_cast<f32x4*>(rn + 4 * (tid + 256)) = an1;
        }
    }
    __syncthreads();

    float mnv = 1e30f, mxv = -1e30f, mnn = 1e30f, mxn = -1e30f;
    for (int n = tid; n < NN; n += 256) {
        float v = rv[n]; mnv = fminf(mnv, v); mxv = fmaxf(mxv, v);
        float u = rn[n]; mnn = fminf(mnn, u); mxn = fmaxf(mxn, u);
    }
    #pragma unroll
    for (int off = 32; off >= 1; off >>= 1) {
        mnv = fminf(mnv, __shfl_xor(mnv, off));
        mxv = fmaxf(mxv, __shfl_xor(mxv, off));
        mnn = fminf(mnn, __shfl_xor(mnn, off));
        mxn = fmaxf(mxn, __shfl_xor(mxn, off));
    }
    if ((tid & 63) == 0) {
        int wid = tid >> 6;
        wred[wid * 4 + 0] = mnv; wred[wid * 4 + 1] = mxv;
        wred[wid * 4 + 2] = mnn; wred[wid * 4 + 3] = mxn;
    }
    if (tid == 0) { sc[0] = 0; sc[1] = 0; }
    __syncthreads();
    mnv = fminf(fminf(wred[0], wred[4]), fminf(wred[8], wred[12]));
    mxv = fmaxf(fmaxf(wred[1], wred[5]), fmaxf(wred[9], wred[13]));
    mnn = fminf(fminf(wred[2], wred[6]), fminf(wred[10], wred[14]));
    mxn = fmaxf(fmaxf(wred[3], wred[7]), fmaxf(wred[11], wred[15]));
    float iv = 1.f / (mxv - mnv), inn = 1.f / (mxn - mnn);

    for (int n = tid; n < NN; n += 256) {
        rv[n] = (rv[n] - mnv) * iv;
        rn[n] = (rn[n] - mnn) * inn;
    }
    for (int i = tid; i < 1024; i += 256) h[i] = 0;
    __syncthreads();
    for (int n = tid; n < NN; n += 256) {
        atomicAdd(&h[binof(rv[n])], 1);
        atomicAdd(&h[binof(rn[n])], 1 << 16);
    }
    __syncthreads();

    int h0 = h[4 * tid], h1 = h[4 * tid + 1], h2 = h[4 * tid + 2], h3 = h[4 * tid + 3];
    tsum[tid] = h0 + h1 + h2 + h3;
    __syncthreads();
    for (int off = 1; off < 256; off <<= 1) {
        int add = (tid + off < 256) ? tsum[tid + off] : 0;
        __syncthreads();
        tsum[tid] += add;
        __syncthreads();
    }
    {
        int scur = tsum[tid];
        int hk[4] = {h0, h1, h2, h3};
        #pragma unroll
        for (int k = 0; k < 4; ++k) {
            int snext = scur - hk[k];
            int scv = scur & 0xffff, ncv = snext & 0xffff;
            int sh = scur >> 16, nh = snext >> 16;
            if (scv >= NTOK && ncv < NTOK) { sc[2] = 4 * tid + k; sc[3] = ncv; }
            if (sh >= NTOK && nh < NTOK) { sc[4] = 4 * tid + k; sc[5] = nh; }
            scur = snext;
        }
    }
    __syncthreads();
    int bsv = sc[2], abv = sc[3], bsn = sc[4], abn = sc[5];

    for (int n = tid; n < NN; n += 256) {
        float v = rv[n]; int bv = binof(v);
        if (bv < bsv) rv[n] = 0.f;
        else if (bv == bsv) {
            int s = atomicAdd(&sc[0], 1);
            if (s < BCAP) { lval_v[s] = v; lidx_v[s] = n; }
        }
        float u = rn[n]; int bu = binof(u);
        if (bu < bsn) rn[n] = 0.f;
        else if (bu == bsn) {
            int s = atomicAdd(&sc[1], 1);
            if (s < BCAP) { lval_n[s] = u; lidx_n[s] = n; }
        }
    }
    __syncthreads();
    int Lv = sc[0] < BCAP ? sc[0] : BCAP;
    int Ln = sc[1] < BCAP ? sc[1] : BCAP;
    for (int i = tid; i < Lv; i += 256) {
        float vi = lval_v[i]; int ni = lidx_v[i]; int r = 0;
        for (int j = 0; j < Lv; ++j) {
            float vj = lval_v[j]; int nj = lidx_v[j];
            r += (vj > vi || (vj == vi && nj < ni)) ? 1 : 0;
        }
        rv[ni] = (r < NTOK - abv) ? vi : 0.f;
    }
    for (int i = tid; i < Ln; i += 256) {
        float vi = lval_n[i]; int ni = lidx_n[i]; int r = 0;
        for (int j = 0; j < Ln; ++j) {
            float vj = lval_n[j]; int nj = lidx_n[j];
            r += (vj > vi || (vj == vi && nj < ni)) ? 1 : 0;
        }
        rn[ni] = (r < NTOK - abn) ? vi : 0.f;
    }
    __syncthreads();
    for (int n = tid; n < NN; n += 256) cam[b * NN + n] = fmaxf(rv[n], rn[n]);
}

// ---------------- K5: MFMA implicit-GEMM conv + fused relu/score + cam ------
// R2-proven core at (256,3). R9: xp is halo-free; halo lanes redirect their
// per-lane GLDS global source to zbuf (1 KB of zeros) -- MFMA inputs are
// bit-identical to the padded layout.
__global__ __launch_bounds__(256, 3) void k_gemm(
        const __hip_bfloat16* __restrict__ xp, const __hip_bfloat16* __restrict__ wb,
        const float* __restrict__ convb, const float* __restrict__ scorew,
        float* __restrict__ pl,
        const float* __restrict__ x,
        const float* __restrict__ pv, const float* __restrict__ pn,
        const float* __restrict__ wpv, const float* __restrict__ wpn,
        float* __restrict__ cam, const __hip_bfloat16* __restrict__ zb) {
    __shared__ char smem[32768];
    int tid = threadIdx.x;
    int bid = blockIdx.x;        // 0..3199
    if (bid < 64) { cam_block(bid, tid, smem, x, pv, pn, wpv, wpn, cam); return; }
    char* As = smem;             // [row 0..127][seg 0..7] bf16x8, swizzled
    char* Bs = smem + 16384;     // [d'  0..127][seg 0..7]
    int gid = bid - 64;          // 0..3135
    int xcd = gid & 7;
    int local = gid >> 3;        // 0..391
    int mtile = xcd * 98 + (local >> 2);
    int nblk = local & 3;
    int m0 = mtile * 128;
    int n0 = nblk * 128;
    int lane = tid & 63, wv = tid >> 6;
    int wm = wv >> 1, wn = wv & 1;
    int ln = lane & 15, qd = lane >> 4;

    int rrow = tid >> 3;
    int segst = ((tid & 7) ^ (rrow & 7)) * 8;     // element offset in row
    int bt_[4], hh_[4], ww_[4];
    const __hip_bfloat16* bptr[4];
    #pragma unroll
    for (int j = 0; j < 4; ++j) {
        int m = m0 + j * 32 + rrow;
        int bt = m / HW, q = m - bt * HW;
        bt_[j] = bt; hh_[j] = q / WW; ww_[j] = q - (q / WW) * WW;
        bptr[j] = wb + (size_t)(n0 + j * 32 + rrow) * 256 + segst;
    }

    int swz = ln & 7;
    int offk[2] = {((0 + qd) ^ swz) * 16, ((4 + qd) ^ swz) * 16};

    f32x4 acc[4][4];
    #pragma unroll
    for (int i = 0; i < 4; ++i)
        #pragma unroll
        for (int j = 0; j < 4; ++j) acc[i][j] = (f32x4){0.f, 0.f, 0.f, 0.f};

    for (int kk = 0; kk < 9; ++kk) {
        int kh = kk / 3, kw = kk - (kk / 3) * 3;
        const __hip_bfloat16* aptr[4];
        #pragma unroll
        for (int j = 0; j < 4; ++j) {
            int ph = hh_[j] + kh, pw = ww_[j] + kw;       // 0..8 each
            bool halo = (ph == 0) | (ph == 8) | (pw == 0) | (pw == 8);
            aptr[j] = halo ? zb
                : xp + ((size_t)bt_[j] * HW + (ph - 1) * 7 + (pw - 1)) * 256 + segst;
        }
        const size_t boff = (size_t)kk * (DD * 256);
        #pragma unroll
        for (int c0 = 0; c0 < 256; c0 += 64) {
            __syncthreads();
            #pragma unroll
            for (int j = 0; j < 4; ++j) {
                GLDS(aptr[j] + c0, As + j * 4096 + tid * 16);
                GLDS(bptr[j] + boff + c0, Bs + j * 4096 + tid * 16);
            }
            __syncthreads();
            #pragma unroll
            for (int k2 = 0; k2 < 2; ++k2) {
                bf16x8 af[4], bfr[4];
                #pragma unroll
                for (int i = 0; i < 4; ++i)
                    af[i] = *(const bf16x8*)(As + (wm * 64 + i * 16 + ln) * 128 + offk[k2]);
                #pragma unroll
                for (int j = 0; j < 4; ++j)
                    bfr[j] = *(const bf16x8*)(Bs + (wn * 64 + j * 16 + ln) * 128 + offk[k2]);
                #pragma unroll
                for (int i = 0; i < 4; ++i)
                    #pragma unroll
                    for (int j = 0; j < 4; ++j)
                        acc[i][j] = __builtin_amdgcn_mfma_f32_16x16x32_bf16(af[i], bfr[j], acc[i][j], 0, 0, 0);
            }
        }
    }

    float swr[4], cbr[4];
    #pragma unroll
    for (int j = 0; j < 4; ++j) {
        int n = n0 + wn * 64 + j * 16 + ln;
        swr[j] = scorew[n];
        cbr[j] = convb[n];
    }
    float* dst = pl + (size_t)(nblk * 2 + wn) * TOTAL;
    #pragma unroll
    for (int i = 0; i < 4; ++i) {
        #pragma unroll
        for (int r = 0; r < 4; ++r) {
            float v = 0.f;
            #pragma unroll
            for (int j = 0; j < 4; ++j) {
                float h1 = acc[i][j][r] + cbr[j];
                h1 = h1 > 0.f ? h1 : 0.f;
                v = fmaf(swr[j], h1, v);
            }
            v += __shfl_xor(v, 1);
            v += __shfl_xor(v, 2);
            v += __shfl_xor(v, 4);
            v += __shfl_xor(v, 8);
            if (ln == 0)
                dst[m0 + wm * 64 + i * 16 + qd * 4 + r] = v;
        }
    }
}

// ---------------- K6: slot-sum + BCE + grid reduction (last block) ----------
__global__ __launch_bounds__(256) void k_bce(
        const float* __restrict__ pl, const float* __restrict__ cam,
        const float* __restrict__ sb, float* __restrict__ part,
        int* __restrict__ counter, float* __restrict__ out) {
    __shared__ float sbuf[256];
    __shared__ int isLast;
    int tid = threadIdx.x;
    int m = blockIdx.x * 256 + tid;
    float l = sb[0];
    #pragma unroll
    for (int s = 0; s < 8; ++s) l += pl[(size_t)s * TOTAL + m];
    float y = cam[m];
    float v = fmaxf(l, 0.f) - l * y + log1pf(expf(-fabsf(l)));
    sbuf[tid] = v; __syncthreads();
    for (int k = 128; k > 0; k >>= 1) {
        if (tid < k) sbuf[tid] += sbuf[tid + k];
        __syncthreads();
    }
    if (tid == 0) {
        part[blockIdx.x] = sbuf[0];
        __threadfence();
        int d = atomicAdd(counter, 1);
        isLast = (d == 391);
    }
    __syncthreads();
    if (isLast) {
        float s = 0.f;
        for (int i = tid; i < 392; i += 256) s += part[i];
        sbuf[tid] = s; __syncthreads();
        for (int k = 128; k > 0; k >>= 1) {
            if (tid < k) sbuf[tid] += sbuf[tid + k];
            __syncthreads();
        }
        if (tid == 0) out[0] = sbuf[0] * (1.0f / (float)TOTAL);
    }
}

extern "C" void kernel_launch(void* const* d_in, const int* in_sizes, int n_in,
                              void* d_out, int out_size, void* d_ws, size_t ws_size,
                              hipStream_t stream) {
    const float* x   = (const float*)d_in[0];
    const float* pv  = (const float*)d_in[1];
    const float* pn  = (const float*)d_in[2];
    const float* wpv = (const float*)d_in[3];
    const float* wpn = (const float*)d_in[4];
    const float* cw  = (const float*)d_in[5];
    const float* cb  = (const float*)d_in[6];
    const float* sw  = (const float*)d_in[7];
    const float* sb  = (const float*)d_in[8];

    char* w8 = (char*)d_ws;
    __hip_bfloat16* xp  = (__hip_bfloat16*)w8;                  // 51,380,224 B (49-pos)
    __hip_bfloat16* wb  = (__hip_bfloat16*)(w8 + 51380224);     //  2,359,296 B
    float* pl      = (float*)(w8 + 53739520);                   //  3,211,264 B
    float* cam     = (float*)(w8 + 56950784);                   //    401,408 B
    float* part    = (float*)(w8 + 57352192);                   //      1,568 B
    int*   counter = (int*)(w8 + 57353760);                     //          4 B
    float* zbuf    = (float*)(w8 + 57353776);                   //      1,024 B (16-aligned)

    k_tr<<<2048, 256, 0, stream>>>(x, xp, cw, wb, counter, zbuf);
    k_gemm<<<64 + 3136, 256, 0, stream>>>(xp, wb, cb, sw, pl,
                                          x, pv, pn, wpv, wpn, cam,
                                          (const __hip_bfloat16*)zbuf);
    k_bce<<<392, 256, 0, stream>>>(pl, cam, sb, part, counter, (float*)d_out);
}